// Round 12
// baseline (2543.765 us; speedup 1.0000x reference)
//
#include <hip/hip_runtime.h>
#include <hip/hip_bf16.h>
#include <math.h>

#define NN 100000
#define NE 1600000
#define NP 500000
#define HD 128
#define NPB 128                    // nodes per bucket (pow2)
#define NB 782                     // ceil(NN/NPB)
#define CAP 2560                   // bucket capacity (mean 2048, +11 sigma)
#define CHUNK 4096                 // edges per binning workgroup
#define NWG 391                    // ceil(NE/CHUNK)
#define GEMMB 1563                 // gemm blocks = ceil(NN/64)
#define ABB_PROD 1954              // gemm+binA blocks (0..1953); binB = 1954..2735
#define GATB 6256                  // gatherR blocks = NB*8
#define QAGB 391                   // qagg blocks = NB*NPB/256
#define PRB 977                    // pairs blocks (2 pairs/thread)

typedef __attribute__((ext_vector_type(8))) short short8;   // 8 bf16 = 4 VGPRs
typedef __attribute__((ext_vector_type(4))) float f32x4;

// ---- bf16 helpers ----
__device__ __forceinline__ float bf_lo(unsigned int u) { return __uint_as_float(u << 16); }
__device__ __forceinline__ float bf_hi(unsigned int u) { return __uint_as_float(u & 0xffff0000u); }
__device__ __forceinline__ unsigned short bf16_rne(float f) {
  unsigned int u = __float_as_uint(f);
  u = (u + 0x7fffu + ((u >> 16) & 1u)) >> 16;
  return (unsigned short)u;
}
// ax[j] += s * bf16[j]  (FMA — same VALU cost as plain add)
__device__ __forceinline__ void acc_row8s(float* ax, uint4 u, float s) {
  ax[0] = fmaf(s, bf_lo(u.x), ax[0]); ax[1] = fmaf(s, bf_hi(u.x), ax[1]);
  ax[2] = fmaf(s, bf_lo(u.y), ax[2]); ax[3] = fmaf(s, bf_hi(u.y), ax[3]);
  ax[4] = fmaf(s, bf_lo(u.z), ax[4]); ax[5] = fmaf(s, bf_hi(u.z), ax[5]);
  ax[6] = fmaf(s, bf_lo(u.w), ax[6]); ax[7] = fmaf(s, bf_hi(u.w), ax[7]);
}

// spin-gate helpers (device-scope message passing)
__device__ __forceinline__ void gate_wait(const int* flag, int target, int t) {
  if (t == 0) {
    while (__hip_atomic_load(flag, __ATOMIC_RELAXED, __HIP_MEMORY_SCOPE_AGENT) < target)
      __builtin_amdgcn_s_sleep(2);
  }
  __syncthreads();
  __threadfence();   // acquire side: subsequent loads see producers' stores
}
__device__ __forceinline__ void gate_arrive(int* flag, int t) {
  __threadfence();   // release: all this block's stores visible first
  __syncthreads();
  if (t == 0) atomicAdd(flag, 1);
}

// ---------------- prep: W1 transpose/cast + u-vectors + gcursor/flags init + cnt zero ----
// blocks 0..390: zero cnt[100096]; 391..454: wconv; 455: uvec; 456: gcursor+flags
__global__ __launch_bounds__(256) void k_prep(const float* __restrict__ W1,
                                              unsigned short* __restrict__ Wt,
                                              const float* __restrict__ W2,
                                              const float* __restrict__ Wl,
                                              const float* __restrict__ b2,
                                              float* __restrict__ uv,
                                              int* __restrict__ gcursor,
                                              int* __restrict__ cnt,
                                              int* __restrict__ flags) {
  const int blk = blockIdx.x;
  const int t = threadIdx.x;
  if (blk < 391) {
    cnt[blk * 256 + t] = 0;          // 391*256 = 100096
  } else if (blk < 455) {
    int i = (blk - 391) * 256 + t;   // 16384
    int n = i >> 7, k = i & 127;
    Wt[i] = bf16_rne(W1[k * HD + n]);
  } else if (blk == 455) {
    __shared__ float sh[256];
    const int half = t >> 7;
    const int k = t & 127;
    const float* wl = Wl + half * 128;
    float s = 0.f;
    for (int c = 0; c < 128; ++c) s += W2[k * HD + c] * wl[c];
    uv[half * 128 + k] = s;

    sh[t] = b2[k] * Wl[half * 128 + k];
    __syncthreads();
    for (int o = 64; o > 0; o >>= 1) {
      if ((t & 127) < o) sh[t] += sh[t + o];
      __syncthreads();
    }
    if (t == 0) uv[256] = sh[0];
    if (t == 128) uv[257] = sh[128];
  } else {
    for (int i = t; i < NB; i += 256) gcursor[i] = i * CAP;
    if (t < 4) flags[t] = 0;
  }
}

// ---------------- fusedABB: GEMM || binA (striped, 0..1953) + binB (1954.., gated) ----
// R12: binB merged into the same dispatch behind a spin-gate on binAdone (flags[0]).
// Deadlock-free: 782 spinners < resident capacity, so producer blocks always progress.
// LDS union (17408B exact): gemm tile[4][16][136] / binA hist+base / binB lbin+lrank+...
__global__ __launch_bounds__(256) void k_fusedABB(const float* __restrict__ X,
                                                  const unsigned short* __restrict__ Wt,
                                                  unsigned short* __restrict__ hs,
                                                  const int* __restrict__ src,
                                                  const int* __restrict__ dst,
                                                  int* __restrict__ gcursor,
                                                  unsigned* __restrict__ binned,
                                                  int2* __restrict__ rows,
                                                  int* __restrict__ col,
                                                  float* __restrict__ dinv,
                                                  int* __restrict__ sortOrd,
                                                  int* __restrict__ flags) {
  __shared__ __align__(16) unsigned char smem[17408];
  const int t = threadIdx.x;
  const int g = blockIdx.x;

  if (g < ABB_PROD && (g % 5) != 0) {
    // ================= GEMM role =================
    const int gemmId = g - g / 5 - 1;   // 0..1562 (dense over g%5!=0)
    unsigned short (*tile)[16][136] = (unsigned short (*)[16][136])smem;
    const int wave = t >> 6;
    const int lane = t & 63;
    const int row0 = gemmId * 64 + wave * 16;
    if (row0 >= NN) return;
    const int lm = lane & 15;
    const int lq = lane >> 4;

    int arow = row0 + lm;
    int arowc = arow < NN ? arow : NN - 1;

    short8 afrag[4];
#pragma unroll
    for (int kc = 0; kc < 4; ++kc) {
      int k0 = kc * 32 + lq * 8;
      const float4* p = (const float4*)(X + (size_t)arowc * HD + k0);
      float4 f0 = p[0], f1 = p[1];
      short8 a;
      a[0] = (short)bf16_rne(f0.x); a[1] = (short)bf16_rne(f0.y);
      a[2] = (short)bf16_rne(f0.z); a[3] = (short)bf16_rne(f0.w);
      a[4] = (short)bf16_rne(f1.x); a[5] = (short)bf16_rne(f1.y);
      a[6] = (short)bf16_rne(f1.z); a[7] = (short)bf16_rne(f1.w);
      afrag[kc] = a;
    }

    f32x4 accs[8];
#pragma unroll
    for (int nt = 0; nt < 8; ++nt) {
      f32x4 acc = {0.f, 0.f, 0.f, 0.f};
      const unsigned short* Wb = Wt + (size_t)(nt * 16 + lm) * HD + lq * 8;
#pragma unroll
      for (int kc = 0; kc < 4; ++kc) {
        short8 bfrag = *(const short8*)(Wb + kc * 32);
        acc = __builtin_amdgcn_mfma_f32_16x16x32_bf16(afrag[kc], bfrag, acc, 0, 0, 0);
      }
      accs[nt] = acc;
    }

#pragma unroll
    for (int nt = 0; nt < 8; ++nt)
#pragma unroll
      for (int r = 0; r < 4; ++r)
        tile[wave][lq * 4 + r][nt * 16 + lm] = bf16_rne(accs[nt][r]);

    const int half = lq >> 1;
    const int ch = lq & 1;
    const int row = row0 + lm;
    if (row < NN) {
      unsigned short* dstp = hs + ((size_t)half * NN + row) * 64 + ch * 32;
#pragma unroll
      for (int j = 0; j < 4; ++j) {
        uint4 v = *(const uint4*)&tile[wave][lm][half * 64 + ch * 32 + j * 8];
        *(uint4*)(dstp + j * 8) = v;
      }
    }
  } else if (g < ABB_PROD) {
    // ================= binA role =================
    const int chunkId = g / 5;         // 0..390
    int* hist = (int*)smem;
    int* base = hist + NB;
    const int e0 = chunkId * CHUNK;

    for (int i = t; i < NB; i += 256) hist[i] = 0;
    __syncthreads();

    int dstv[CHUNK / 256];
    int rank[CHUNK / 256];
#pragma unroll
    for (int k = 0; k < CHUNK / 256; ++k) {
      int e = e0 + k * 256 + t;
      dstv[k] = (e < NE) ? dst[e] : -1;
      rank[k] = (dstv[k] >= 0) ? atomicAdd(&hist[dstv[k] >> 7], 1) : 0;
    }
    __syncthreads();

    for (int i = t; i < NB; i += 256) {
      int c = hist[i];
      base[i] = c ? atomicAdd(&gcursor[i], c) : 0;
    }
    __syncthreads();

#pragma unroll
    for (int k = 0; k < CHUNK / 256; ++k) {
      int d = dstv[k];
      if (d >= 0) {
        int e = e0 + k * 256 + t;
        int pos = base[d >> 7] + rank[k];
        binned[pos] = (unsigned)src[e] | ((unsigned)(d & 127) << 17);
      }
    }
    gate_arrive(&flags[0], t);         // binAdone++
  } else {
    // ================= binB role (gated on binAdone==NWG) =================
    gate_wait(&flags[0], NWG, t);

    unsigned* lbin = (unsigned*)smem;                       // 10240 B
    unsigned short* lrank = (unsigned short*)(smem + 10240); // 5120 B
    int* hcnt = (int*)(smem + 15360);                       // 512 B
    int* sc   = (int*)(smem + 15872);                       // 512 B
    int* lcur = (int*)(smem + 16384);                       // 512 B
    int* h64  = (int*)(smem + 16896);                       // 256 B
    int* s64  = (int*)(smem + 17152);                       // 256 B
    const int b = g - ABB_PROD;        // bucket 0..781
    const int node0 = b * NPB;
    const int node1 = (node0 + NPB > NN) ? NN : node0 + NPB;
    const int nnode = node1 - node0;
    if (t < NPB) hcnt[t] = 0;
    if (t < 64) h64[t] = 0;
    __syncthreads();

    const int gbase = b * CAP;
    const int gend = gcursor[b];
    const int cntB = gend - gbase;
    for (int i = gbase + t; i < gend; i += 256) {
      unsigned en = binned[i];
      lbin[i - gbase] = en;
      lrank[i - gbase] = (unsigned short)atomicAdd(&hcnt[en >> 17], 1);
    }
    __syncthreads();

    int v = (t < NPB) ? hcnt[t] : 0;
    if (t < NPB) sc[t] = v;
    __syncthreads();
#pragma unroll
    for (int o = 1; o < NPB; o <<= 1) {
      int add = (t < NPB && t >= o) ? sc[t - o] : 0;
      __syncthreads();
      if (t < NPB) sc[t] += add;
      __syncthreads();
    }
    if (t < NPB) {
      int rp = gbase + sc[t] - v;
      lcur[t] = rp;
      if (t < nnode) {
        rows[node0 + t] = make_int2(rp, rp + v);
        dinv[node0 + t] = rsqrtf((float)v + 1.0f);
      }
    }

    const int deg = (t < nnode) ? v : 0;
    const int dcl = deg > 63 ? 63 : deg;
    if (t < NPB) atomicAdd(&h64[dcl], 1);
    __syncthreads();
    int hv = (t < 64) ? h64[t] : 0;
    if (t < 64) s64[t] = hv;
    __syncthreads();
#pragma unroll
    for (int o = 1; o < 64; o <<= 1) {
      int add = (t < 64 && t >= o) ? s64[t - o] : 0;
      __syncthreads();
      if (t < 64) s64[t] += add;
      __syncthreads();
    }
    if (t < 64) h64[t] = s64[t] - hv;
    __syncthreads();
    if (t < NPB) {
      int p = atomicAdd(&h64[dcl], 1);
      sortOrd[b * NPB + p] = t;
    }
    __syncthreads();

    for (int i = t; i < cntB; i += 256) {
      unsigned en = lbin[i];
      col[lcur[en >> 17] + (int)lrank[i]] = (int)(en & 0x1FFFF);
    }
  }
}

// ---------------- fusedGQP: gatherR(+qred via cnt) + qagg (gated) + pairs (gated) ----
// gather blocks 0..6255; qagg 6256..6646 (gate gatherdone==6256); pairs 6647..7623
// (gate qaggdone==391). Spinners (1368) < capacity (2048) -> deadlock-free.
__global__ __launch_bounds__(256) void k_fusedGQP(const uint4* __restrict__ hsv,
                                                  const float* __restrict__ dinv,
                                                  const int2* __restrict__ rows,
                                                  const int* __restrict__ col,
                                                  const int* __restrict__ sortOrd,
                                                  const float* __restrict__ b1,
                                                  const float* __restrict__ uv,
                                                  float2* __restrict__ qpart,
                                                  float2* __restrict__ q,
                                                  float2* __restrict__ sv,
                                                  const int* __restrict__ I,
                                                  const int* __restrict__ J,
                                                  const float* __restrict__ blin,
                                                  float* __restrict__ out,
                                                  int* __restrict__ cnt,
                                                  int* __restrict__ flags) {
  const int b = blockIdx.x;
  const int t = threadIdx.x;

  if (b < GATB) {
    // ================= gatherR role (+folded qred) =================
    const int half = b & 1;
    const int slice = (b >> 1) & 3;
    const int g = b >> 3;
    const int gi = t >> 3;
    const int fl = t & 7;
    const int p = gi * 4 + slice;
    const int tloc = sortOrd[g * NPB + p];
    const int node = g * NPB + tloc;
    const bool valid = node < NN;

    int2 be = valid ? rows[node] : make_int2(0, 0);
    const uint4* plane = hsv + (size_t)half * NN * 8;
    const float di = valid ? dinv[node] : 0.f;

    float ax[8] = {0.f, 0.f, 0.f, 0.f, 0.f, 0.f, 0.f, 0.f};
    if (valid) acc_row8s(ax, plane[(size_t)node * 8 + fl], di);

    int e = be.x;
    const int eend = be.y;
    for (; e + 3 < eend; e += 4) {
      int c0 = col[e], c1 = col[e + 1], c2 = col[e + 2], c3 = col[e + 3];
      uint4 u0 = plane[(size_t)c0 * 8 + fl];
      uint4 u1 = plane[(size_t)c1 * 8 + fl];
      uint4 u2 = plane[(size_t)c2 * 8 + fl];
      uint4 u3 = plane[(size_t)c3 * 8 + fl];
      float w0 = dinv[c0], w1 = dinv[c1], w2 = dinv[c2], w3 = dinv[c3];
      acc_row8s(ax, u0, w0); acc_row8s(ax, u1, w1);
      acc_row8s(ax, u2, w2); acc_row8s(ax, u3, w3);
    }
    for (; e < eend; ++e) {
      int c = col[e];
      acc_row8s(ax, plane[(size_t)c * 8 + fl], dinv[c]);
    }

    float s1 = 0.f, s2 = 0.f;
#pragma unroll
    for (int j = 0; j < 8; ++j) {
      int f = half * 64 + fl * 8 + j;
      float h = fmaxf(di * ax[j] + b1[f], 0.f);
      s1 += h * uv[f];
      s2 += h * uv[128 + f];
    }
#pragma unroll
    for (int o = 1; o < 8; o <<= 1) {
      s1 += __shfl_xor(s1, o);
      s2 += __shfl_xor(s2, o);
    }
    if (fl == 0 && valid) {
      float2 mine = make_float2(di * s1, di * s2);
      qpart[(size_t)half * NN + node] = mine;
      __threadfence();
      int old = atomicAdd(&cnt[node], 1);
      if (old == 1) {              // second arriver sums both halves (qred folded)
        __threadfence();
        float2 o2 = qpart[(size_t)(1 - half) * NN + node];
        q[node] = make_float2(mine.x + o2.x, mine.y + o2.y);
      }
    }
    gate_arrive(&flags[1], t);     // gatherdone++
  } else if (b < GATB + QAGB) {
    // ================= qagg role (gated on gatherdone==GATB) =================
    gate_wait(&flags[1], GATB, t);
    const int idx = (b - GATB) * 256 + t;
    const int g2 = idx >> 7;
    const int node = g2 * NPB + sortOrd[idx];
    if (node < NN) {
      int2 be = rows[node];
      float2 a = q[node];
      float a1 = a.x, a2 = a.y;
      int e = be.x;
      const int eend = be.y;
      for (; e + 3 < eend; e += 4) {
        float2 q0 = q[col[e]], q1 = q[col[e + 1]];
        float2 q2 = q[col[e + 2]], q3 = q[col[e + 3]];
        a1 += (q0.x + q1.x) + (q2.x + q3.x);
        a2 += (q0.y + q1.y) + (q2.y + q3.y);
      }
      for (; e < eend; ++e) {
        float2 qq = q[col[e]];
        a1 += qq.x; a2 += qq.y;
      }
      float di = dinv[node];
      sv[node] = make_float2(a1 * di + uv[256], a2 * di + uv[257]);
    }
    gate_arrive(&flags[2], t);     // qaggdone++
  } else {
    // ================= pairs role (gated on qaggdone==QAGB) =================
    gate_wait(&flags[2], QAGB, t);
    int p0 = ((b - GATB - QAGB) * 256 + t) * 2;
    if (p0 + 1 < NP) {
      int2 ii = *(const int2*)(I + p0);
      int2 jj = *(const int2*)(J + p0);
      float bb = blin[0];
      float v0 = sv[ii.x].x + sv[jj.x].y + bb;
      float v1 = sv[ii.y].x + sv[jj.y].y + bb;
      *(float2*)(out + p0) = make_float2(1.f / (1.f + __expf(-v0)),
                                         1.f / (1.f + __expf(-v1)));
    } else if (p0 < NP) {
      float v = sv[I[p0]].x + sv[J[p0]].y + blin[0];
      out[p0] = 1.f / (1.f + __expf(-v));
    }
  }
}

extern "C" void kernel_launch(void* const* d_in, const int* in_sizes, int n_in,
                              void* d_out, int out_size, void* d_ws, size_t ws_size,
                              hipStream_t stream) {
  const float* x     = (const float*)d_in[0];
  const int*   eidx  = (const int*)d_in[1];
  const int*   Iidx  = (const int*)d_in[2];
  const int*   Jidx  = (const int*)d_in[3];
  const float* W1    = (const float*)d_in[4];
  const float* b1    = (const float*)d_in[5];
  const float* W2    = (const float*)d_in[6];
  const float* b2    = (const float*)d_in[7];
  const float* Wlin  = (const float*)d_in[8];
  const float* blin  = (const float*)d_in[9];
  const int* src = eidx;
  const int* dst = eidx + NE;

  // workspace layout: hs FIRST so half-rows are 128B-aligned (one line each)
  unsigned short* hs = (unsigned short*)d_ws;         // NN*HD bf16 = 25.6 MB (2 halves)
  float* dinv  = (float*)(hs + (size_t)NN * HD);      // 100000
  float* sv    = dinv + 100000;                       // 200000 (float2/node)
  float* qbuf  = sv + 200000;                         // 200000 (float2/node)
  float* qpart = qbuf + 200000;                       // 2*NN float2 = 400000
  float* uv    = qpart + 400000;                      // 264
  unsigned short* wt1 = (unsigned short*)(uv + 264);  // 16384 bf16
  int2* rows   = (int2*)(wt1 + 16384);                // NN int2 (8B-aligned)
  int* col     = (int*)(rows + NN);                   // NB*CAP = 2001920
  int* gcursor = col + NB * CAP;                      // NB (pad 784)
  int* sortOrd = gcursor + 784;                       // NB*NPB = 100096
  unsigned* binned = (unsigned*)(sortOrd + NB * NPB); // NB*CAP x 4B
  int* cnt     = (int*)(binned + NB * CAP);           // 100096 (qred arrivals)
  int* flags   = cnt + 100096;                        // 4 (binAdone, gatherdone, qaggdone)

  float* out = (float*)d_out;

  // ---- prep: weights + gcursor + flags + cnt zero ----
  k_prep<<<457, 256, 0, stream>>>(W1, wt1, W2, Wlin, b2, uv, gcursor, cnt, flags);

  // ---- dispatch 2: GEMM || binA -> (gate) binB ----
  k_fusedABB<<<ABB_PROD + NB, 256, 0, stream>>>(x, wt1, hs, src, dst, gcursor, binned,
                                                rows, col, dinv, sortOrd, flags);

  // ---- dispatch 3: gatherR(+qred) -> (gate) qagg -> (gate) pairs ----
  k_fusedGQP<<<GATB + QAGB + PRB, 256, 0, stream>>>((const uint4*)hs, dinv, rows, col,
                                                    sortOrd, b1, uv, (float2*)qpart,
                                                    (float2*)qbuf, (float2*)sv,
                                                    Iidx, Jidx, blin, out, cnt, flags);
}

// Round 13
// 269.540 us; speedup vs baseline: 9.4374x; 9.4374x over previous
//
#include <hip/hip_runtime.h>
#include <hip/hip_bf16.h>
#include <math.h>

#define NN 100000
#define NE 1600000
#define NP 500000
#define HD 128
#define NPB 128                    // nodes per bucket (pow2)
#define NB 782                     // ceil(NN/NPB)
#define CAP 2560                   // bucket capacity (mean 2048, +11 sigma)
#define CHUNK 4096                 // edges per binning workgroup
#define NWG 391                    // ceil(NE/CHUNK)
#define GEMMB 1563                 // gemm blocks in fused kernel = ceil(NN/64)
#define GCSTR 32                   // gcursor stride (ints): 1 bucket per 128B sector

typedef __attribute__((ext_vector_type(8))) short short8;   // 8 bf16 = 4 VGPRs
typedef __attribute__((ext_vector_type(4))) float f32x4;

// ---- bf16 helpers ----
__device__ __forceinline__ float bf_lo(unsigned int u) { return __uint_as_float(u << 16); }
__device__ __forceinline__ float bf_hi(unsigned int u) { return __uint_as_float(u & 0xffff0000u); }
__device__ __forceinline__ unsigned short bf16_rne(float f) {
  unsigned int u = __float_as_uint(f);
  u = (u + 0x7fffu + ((u >> 16) & 1u)) >> 16;
  return (unsigned short)u;
}
// ax[j] += s * bf16[j]  (FMA — same VALU cost as plain add)
__device__ __forceinline__ void acc_row8s(float* ax, uint4 u, float s) {
  ax[0] = fmaf(s, bf_lo(u.x), ax[0]); ax[1] = fmaf(s, bf_hi(u.x), ax[1]);
  ax[2] = fmaf(s, bf_lo(u.y), ax[2]); ax[3] = fmaf(s, bf_hi(u.y), ax[3]);
  ax[4] = fmaf(s, bf_lo(u.z), ax[4]); ax[5] = fmaf(s, bf_hi(u.z), ax[5]);
  ax[6] = fmaf(s, bf_lo(u.w), ax[6]); ax[7] = fmaf(s, bf_hi(u.w), ax[7]);
}

// ---------------- prep (fused): W1 transpose/cast + u-vectors + gcursor init ----------------
__global__ __launch_bounds__(256) void k_prep(const float* __restrict__ W1,
                                              unsigned short* __restrict__ Wt,
                                              const float* __restrict__ W2,
                                              const float* __restrict__ Wl,
                                              const float* __restrict__ b2,
                                              float* __restrict__ uv,
                                              int* __restrict__ gcursor) {
  const int blk = blockIdx.x;
  const int t = threadIdx.x;
  if (blk < 64) {
    int i = blk * 256 + t;           // 16384
    int n = i >> 7, k = i & 127;
    Wt[i] = bf16_rne(W1[k * HD + n]);
  } else if (blk == 64) {
    // u-vectors: u1 = W2@Wl[:128], u2 = W2@Wl[128:], c1/c2 = b2.Wl
    __shared__ float sh[256];
    const int half = t >> 7;
    const int k = t & 127;
    const float* wl = Wl + half * 128;
    float s = 0.f;
    for (int c = 0; c < 128; ++c) s += W2[k * HD + c] * wl[c];
    uv[half * 128 + k] = s;

    sh[t] = b2[k] * Wl[half * 128 + k];
    __syncthreads();
    for (int o = 64; o > 0; o >>= 1) {
      if ((t & 127) < o) sh[t] += sh[t + o];
      __syncthreads();
    }
    if (t == 0) uv[256] = sh[0];
    if (t == 128) uv[257] = sh[128];
  } else {
    // padded cursor init: bucket i lives at gcursor[i*GCSTR] (128B apart -> no
    // cache-line false sharing on the 300K allocator atomics in binA)
    for (int i = t; i < NB; i += 256) gcursor[i * GCSTR] = i * CAP;
  }
}

// ---------------- fused: GEMM || binA, roles INTERLEAVED by blockIdx ----------------
// binA on every 5th block (g%5==0, 391 total), gemm on the rest (1563); both
// populations co-resident from t=0 (R11). R13: gcursor padded to 128B/bucket —
// the allocator atomicAdds were serializing ~6256 RMW ops per cache line.
__global__ __launch_bounds__(256) void k_fusedAG(const float* __restrict__ X,
                                                 const unsigned short* __restrict__ Wt,
                                                 unsigned short* __restrict__ hs,
                                                 const int* __restrict__ src,
                                                 const int* __restrict__ dst,
                                                 int* __restrict__ gcursor,
                                                 unsigned* __restrict__ binned) {
  __shared__ __align__(16) unsigned char smem[17408];
  const int t = threadIdx.x;
  const int g = blockIdx.x;
  const bool isBin = (g % 5 == 0);   // 391 binA blocks: g = 0,5,...,1950

  if (!isBin) {
    // ================= GEMM role =================
    const int gemmId = g - g / 5 - 1;   // 0..1562 (dense over g%5!=0)
    unsigned short (*tile)[16][136] = (unsigned short (*)[16][136])smem;
    const int wave = t >> 6;
    const int lane = t & 63;
    const int row0 = gemmId * 64 + wave * 16;
    if (row0 >= NN) return;
    const int lm = lane & 15;   // A-row / C-col
    const int lq = lane >> 4;   // quad

    int arow = row0 + lm;
    int arowc = arow < NN ? arow : NN - 1;  // clamp (stores are guarded)

    short8 afrag[4];
#pragma unroll
    for (int kc = 0; kc < 4; ++kc) {
      int k0 = kc * 32 + lq * 8;
      const float4* p = (const float4*)(X + (size_t)arowc * HD + k0);
      float4 f0 = p[0], f1 = p[1];
      short8 a;
      a[0] = (short)bf16_rne(f0.x); a[1] = (short)bf16_rne(f0.y);
      a[2] = (short)bf16_rne(f0.z); a[3] = (short)bf16_rne(f0.w);
      a[4] = (short)bf16_rne(f1.x); a[5] = (short)bf16_rne(f1.y);
      a[6] = (short)bf16_rne(f1.z); a[7] = (short)bf16_rne(f1.w);
      afrag[kc] = a;
    }

    f32x4 accs[8];
#pragma unroll
    for (int nt = 0; nt < 8; ++nt) {
      f32x4 acc = {0.f, 0.f, 0.f, 0.f};
      const unsigned short* Wb = Wt + (size_t)(nt * 16 + lm) * HD + lq * 8;
#pragma unroll
      for (int kc = 0; kc < 4; ++kc) {
        short8 bfrag = *(const short8*)(Wb + kc * 32);
        acc = __builtin_amdgcn_mfma_f32_16x16x32_bf16(afrag[kc], bfrag, acc, 0, 0, 0);
      }
      accs[nt] = acc;
    }

    // stage the wave's 16x128 bf16 tile in LDS (unscaled h)
#pragma unroll
    for (int nt = 0; nt < 8; ++nt)
#pragma unroll
      for (int r = 0; r < 4; ++r)
        tile[wave][lq * 4 + r][nt * 16 + lm] = bf16_rne(accs[nt][r]);

    // coalesced writeout: lane (lm, q): half = q>>1, chunk = q&1; 4 x 16B per lane
    const int half = lq >> 1;
    const int ch = lq & 1;
    const int row = row0 + lm;
    if (row < NN) {
      unsigned short* dstp = hs + ((size_t)half * NN + row) * 64 + ch * 32;
#pragma unroll
      for (int j = 0; j < 4; ++j) {
        uint4 v = *(const uint4*)&tile[wave][lm][half * 64 + ch * 32 + j * 8];
        *(uint4*)(dstp + j * 8) = v;
      }
    }
  } else {
    // ================= binA role =================
    const int chunkId = g / 5;         // 0..390
    int* hist = (int*)smem;            // NB ints
    int* base = hist + NB;             // NB ints (total 6256B <= 17408)
    const int e0 = chunkId * CHUNK;

    for (int i = t; i < NB; i += 256) hist[i] = 0;
    __syncthreads();

    int dstv[CHUNK / 256];
    int rank[CHUNK / 256];
#pragma unroll
    for (int k = 0; k < CHUNK / 256; ++k) {
      int e = e0 + k * 256 + t;
      dstv[k] = (e < NE) ? dst[e] : -1;
      rank[k] = (dstv[k] >= 0) ? atomicAdd(&hist[dstv[k] >> 7], 1) : 0;
    }
    __syncthreads();

    for (int i = t; i < NB; i += 256) {
      int c = hist[i];
      base[i] = c ? atomicAdd(&gcursor[i * GCSTR], c) : 0;
    }
    __syncthreads();

#pragma unroll
    for (int k = 0; k < CHUNK / 256; ++k) {
      int d = dstv[k];
      if (d >= 0) {
        int e = e0 + k * 256 + t;
        int pos = base[d >> 7] + rank[k];
        binned[pos] = (unsigned)src[e] | ((unsigned)(d & 127) << 17);
      }
    }
  }
}

// ---- binB: per-node count -> rows + dinv + degree-sorted order, then CSR placement ----
// Entries + per-entry ranks staged in LDS during the count pass; placement is atomic-free.
__global__ __launch_bounds__(256) void k_binB(const unsigned* __restrict__ binned,
                                              const int* __restrict__ gcursor,
                                              int2* __restrict__ rows,
                                              int* __restrict__ col,
                                              float* __restrict__ dinv,
                                              int* __restrict__ sortOrd) {
  __shared__ unsigned lbin[CAP];
  __shared__ unsigned short lrank[CAP];
  __shared__ int hcnt[NPB];
  __shared__ int sc[NPB];
  __shared__ int lcur[NPB];
  __shared__ int h64[64];
  __shared__ int s64[64];
  const int b = blockIdx.x;
  const int t = threadIdx.x;
  const int node0 = b * NPB;
  const int node1 = (node0 + NPB > NN) ? NN : node0 + NPB;
  const int nnode = node1 - node0;
  if (t < NPB) hcnt[t] = 0;
  if (t < 64) h64[t] = 0;
  __syncthreads();

  const int gbase = b * CAP;
  const int gend = gcursor[b * GCSTR];   // after binA: b*CAP + bucket count
  const int cnt = gend - gbase;
  for (int i = gbase + t; i < gend; i += 256) {
    unsigned en = binned[i];
    lbin[i - gbase] = en;
    lrank[i - gbase] = (unsigned short)atomicAdd(&hcnt[en >> 17], 1);
  }
  __syncthreads();

  int v = (t < NPB) ? hcnt[t] : 0;
  if (t < NPB) sc[t] = v;
  __syncthreads();
#pragma unroll
  for (int o = 1; o < NPB; o <<= 1) {
    int add = (t < NPB && t >= o) ? sc[t - o] : 0;
    __syncthreads();
    if (t < NPB) sc[t] += add;
    __syncthreads();
  }
  if (t < NPB) {
    int rp = gbase + sc[t] - v;   // exclusive prefix within bucket
    lcur[t] = rp;                 // placement base (atomic-free)
    if (t < nnode) {
      rows[node0 + t] = make_int2(rp, rp + v);
      dinv[node0 + t] = rsqrtf((float)v + 1.0f);
    }
  }

  // ---- counting sort of the 128 local nodes by degree (invalid t -> deg 0) ----
  const int deg = (t < nnode) ? v : 0;
  const int dcl = deg > 63 ? 63 : deg;
  if (t < NPB) atomicAdd(&h64[dcl], 1);
  __syncthreads();
  int hv = (t < 64) ? h64[t] : 0;
  if (t < 64) s64[t] = hv;
  __syncthreads();
#pragma unroll
  for (int o = 1; o < 64; o <<= 1) {
    int add = (t < 64 && t >= o) ? s64[t - o] : 0;
    __syncthreads();
    if (t < 64) s64[t] += add;
    __syncthreads();
  }
  if (t < 64) h64[t] = s64[t] - hv;  // exclusive base -> cursor
  __syncthreads();
  if (t < NPB) {
    int p = atomicAdd(&h64[dcl], 1);
    sortOrd[b * NPB + p] = t;
  }
  __syncthreads();

  for (int i = t; i < cnt; i += 256) {
    unsigned en = lbin[i];
    col[lcur[en >> 17] + (int)lrank[i]] = (int)(en & 0x1FFFF);
  }
}

// ---------------- half-row gather: 8 lanes per node, one full 128B line per edge ----------------
// hs unscaled: apply dinv[src] per edge (broadcast 4B L2 load; table 400KB resident).
// acc becomes FMA (same VALU cost). Stratified degree-sorted positions keep waves uniform.
__global__ __launch_bounds__(256) void k_gatherR(const uint4* __restrict__ hsv,
                                                 const float* __restrict__ dinv,
                                                 const int2* __restrict__ rows,
                                                 const int* __restrict__ col,
                                                 const int* __restrict__ sortOrd,
                                                 const float* __restrict__ b1,
                                                 const float* __restrict__ uv,
                                                 float2* __restrict__ qpart) {
  const int half = blockIdx.x & 1;     // feature half
  const int slice = (blockIdx.x >> 1) & 3;  // position slice
  const int g = blockIdx.x >> 3;       // bucket
  const int t = threadIdx.x;
  const int gi = t >> 3;               // group 0..31 (one node each)
  const int fl = t & 7;                // lane in group: local feats [fl*8, fl*8+8)
  const int p = gi * 4 + slice;        // stratified sorted position
  const int tloc = sortOrd[g * NPB + p];
  const int node = g * NPB + tloc;
  const bool valid = node < NN;

  int2 be = valid ? rows[node] : make_int2(0, 0);
  const uint4* plane = hsv + (size_t)half * NN * 8;
  const float di = valid ? dinv[node] : 0.f;

  float ax[8] = {0.f, 0.f, 0.f, 0.f, 0.f, 0.f, 0.f, 0.f};
  if (valid) acc_row8s(ax, plane[(size_t)node * 8 + fl], di);  // self: di*h[n]

  int e = be.x;
  const int eend = be.y;
  for (; e + 3 < eend; e += 4) {
    int c0 = col[e], c1 = col[e + 1], c2 = col[e + 2], c3 = col[e + 3];
    uint4 u0 = plane[(size_t)c0 * 8 + fl];
    uint4 u1 = plane[(size_t)c1 * 8 + fl];
    uint4 u2 = plane[(size_t)c2 * 8 + fl];
    uint4 u3 = plane[(size_t)c3 * 8 + fl];
    float w0 = dinv[c0], w1 = dinv[c1], w2 = dinv[c2], w3 = dinv[c3];
    acc_row8s(ax, u0, w0); acc_row8s(ax, u1, w1);
    acc_row8s(ax, u2, w2); acc_row8s(ax, u3, w3);
  }
  for (; e < eend; ++e) {
    int c = col[e];
    acc_row8s(ax, plane[(size_t)c * 8 + fl], dinv[c]);
  }

  // epilogue: relu + projection over own 8 feats, reduce across the 8-lane group
  float s1 = 0.f, s2 = 0.f;
#pragma unroll
  for (int j = 0; j < 8; ++j) {
    int f = half * 64 + fl * 8 + j;
    float h = fmaxf(di * ax[j] + b1[f], 0.f);
    s1 += h * uv[f];
    s2 += h * uv[128 + f];
  }
#pragma unroll
  for (int o = 1; o < 8; o <<= 1) {
    s1 += __shfl_xor(s1, o);
    s2 += __shfl_xor(s2, o);
  }
  if (fl == 0 && valid) qpart[(size_t)half * NN + node] = make_float2(di * s1, di * s2);
}

// ---------------- qagg: conv2+score collapsed; reads qpart halves directly ----------------
// R13: k_qred removed. q[c] == qp0[c]+qp1[c]; both tables 800KB -> L2-resident, +1 load/edge.
// Degree-sorted thread->node mapping (sortOrd) for wave-uniform inner-loop lengths.
__global__ __launch_bounds__(256) void k_qagg(const float2* __restrict__ qp0,
                                              const float2* __restrict__ qp1,
                                              const float* __restrict__ dinv,
                                              const int2* __restrict__ rows,
                                              const int* __restrict__ col,
                                              const int* __restrict__ sortOrd,
                                              const float* __restrict__ uv,
                                              float2* __restrict__ sv) {
  const int idx = blockIdx.x * 256 + threadIdx.x;   // grid covers NB*NPB = 100096
  const int g = idx >> 7;
  const int node = g * NPB + sortOrd[idx];
  if (node >= NN) return;
  int2 be = rows[node];
  float2 a0 = qp0[node], b0 = qp1[node];
  float a1 = a0.x + b0.x, a2 = a0.y + b0.y;
  int e = be.x;
  const int eend = be.y;
  for (; e + 3 < eend; e += 4) {
    int c0 = col[e], c1 = col[e + 1], c2 = col[e + 2], c3 = col[e + 3];
    float2 p0 = qp0[c0], q0 = qp1[c0];
    float2 p1 = qp0[c1], q1 = qp1[c1];
    float2 p2 = qp0[c2], q2 = qp1[c2];
    float2 p3 = qp0[c3], q3 = qp1[c3];
    a1 += (p0.x + q0.x) + (p1.x + q1.x) + (p2.x + q2.x) + (p3.x + q3.x);
    a2 += (p0.y + q0.y) + (p1.y + q1.y) + (p2.y + q2.y) + (p3.y + q3.y);
  }
  for (; e < eend; ++e) {
    int c = col[e];
    float2 p = qp0[c], q = qp1[c];
    a1 += p.x + q.x; a2 += p.y + q.y;
  }
  float di = dinv[node];
  sv[node] = make_float2(a1 * di + uv[256], a2 * di + uv[257]);
}

// ---------------- pair outputs: 2 pairs/thread, int2/float2 coalesced ----------------
__global__ void k_pairs(const float2* __restrict__ s, const int* __restrict__ I,
                        const int* __restrict__ J, const float* __restrict__ blin,
                        float* __restrict__ out, int np) {
  int p0 = (blockIdx.x * 256 + threadIdx.x) * 2;
  if (p0 + 1 < np) {
    int2 ii = *(const int2*)(I + p0);
    int2 jj = *(const int2*)(J + p0);
    float b = blin[0];
    float v0 = s[ii.x].x + s[jj.x].y + b;
    float v1 = s[ii.y].x + s[jj.y].y + b;
    *(float2*)(out + p0) = make_float2(1.f / (1.f + __expf(-v0)),
                                       1.f / (1.f + __expf(-v1)));
  } else if (p0 < np) {
    float v = s[I[p0]].x + s[J[p0]].y + blin[0];
    out[p0] = 1.f / (1.f + __expf(-v));
  }
}

extern "C" void kernel_launch(void* const* d_in, const int* in_sizes, int n_in,
                              void* d_out, int out_size, void* d_ws, size_t ws_size,
                              hipStream_t stream) {
  const float* x     = (const float*)d_in[0];
  const int*   eidx  = (const int*)d_in[1];
  const int*   Iidx  = (const int*)d_in[2];
  const int*   Jidx  = (const int*)d_in[3];
  const float* W1    = (const float*)d_in[4];
  const float* b1    = (const float*)d_in[5];
  const float* W2    = (const float*)d_in[6];
  const float* b2    = (const float*)d_in[7];
  const float* Wlin  = (const float*)d_in[8];
  const float* blin  = (const float*)d_in[9];
  const int* src = eidx;
  const int* dst = eidx + NE;

  // workspace layout: hs FIRST so half-rows are 128B-aligned (one line each)
  unsigned short* hs = (unsigned short*)d_ws;         // NN*HD bf16 = 25.6 MB (2 halves)
  float* dinv  = (float*)(hs + (size_t)NN * HD);      // 100000
  float* sv    = dinv + 100000;                       // 200000 (float2/node)
  float* qbuf  = sv + 200000;                         // 200000 (float2/node) [unused now]
  float* qpart = qbuf + 200000;                       // 2*NN float2 = 400000
  float* uv    = qpart + 400000;                      // 264
  unsigned short* wt1 = (unsigned short*)(uv + 264);  // 16384 bf16
  int2* rows   = (int2*)(wt1 + 16384);                // NN int2 (8B-aligned)
  int* col     = (int*)(rows + NN);                   // NB*CAP = 2001920
  int* gcursor = col + NB * CAP;                      // NB*GCSTR = 25024 (padded 128B/bucket)
  int* sortOrd = gcursor + NB * GCSTR;                // NB*NPB = 100096
  unsigned* binned = (unsigned*)(sortOrd + NB * NPB); // NB*CAP x 4B

  float* out = (float*)d_out;

  // ---- prep (weight prep + padded cursor init, fused) ----
  k_prep<<<66, 256, 0, stream>>>(W1, wt1, W2, Wlin, b2, uv, gcursor);

  // ---- GEMM (unscaled) || binA, one dispatch, roles interleaved ----
  k_fusedAG<<<GEMMB + NWG, 256, 0, stream>>>(x, wt1, hs, src, dst, gcursor, binned);

  // ---- binB: rows/col/dinv/sortOrd ----
  k_binB<<<NB, 256, 0, stream>>>(binned, gcursor, rows, col, dinv, sortOrd);

  // conv1 aggregation + relu + score projection (8 lanes/node, per-edge dinv[src])
  k_gatherR<<<NB * 8, 256, 0, stream>>>((const uint4*)hs, dinv, rows, col,
                                        sortOrd, b1, uv, (float2*)qpart);

  // conv2 + score head collapsed (degree-sorted; reads qpart halves, no qred)
  k_qagg<<<(NB * NPB) / 256, 256, 0, stream>>>((const float2*)qpart,
                                               (const float2*)(qpart + 2 * NN),
                                               dinv, rows, col, sortOrd, uv,
                                               (float2*)sv);

  // pair outputs (2/thread)
  k_pairs<<<(NP / 2 + 255) / 256, 256, 0, stream>>>((const float2*)sv, Iidx, Jidx, blin, out, NP);
}